// Round 4
// baseline (1096.986 us; speedup 1.0000x reference)
//
#include <hip/hip_runtime.h>

// Trilinear "gridding" scatter:
//   B=32 batches, N=65536 points, scale=128 -> s=64, G=128, grid 128^3 per batch.
//   out[b, (ix*G+iy)*G+iz] += trilinear weight, for the 8 corners of each point.
// One thread per point, 8 atomicAdds. Output zeroed via hipMemsetAsync
// (harness poisons d_out with 0xAA before every timed launch).

__global__ void Gridding_kernel(const float* __restrict__ pts,
                                const int* __restrict__ scale_p,
                                float* __restrict__ out,
                                int total_pts, int out_size) {
    int i = blockIdx.x * blockDim.x + threadIdx.x;
    if (i >= total_pts) return;

    const int scale = scale_p[0];
    const int s = scale >> 1;
    const int G = 2 * s;
    const int gpb = G * G * G;            // grid cells per batch
    const int B = out_size / gpb;
    const int N = total_pts / B;
    const int b = i / N;

    const float fs = (float)s;
    const float x = pts[3 * i + 0] * fs;
    const float y = pts[3 * i + 1] * fs;
    const float z = pts[3 * i + 2] * fs;

    // reference: mask = (x+y+z != 0); masked points get zero weight == skip
    if (x + y + z == 0.0f) return;

    const float flx = floorf(x), fly = floorf(y), flz = floorf(z);
    const float ax = x - flx, ay = y - fly, az = z - flz;
    const int ix = (int)flx + s;
    const int iy = (int)fly + s;
    const int iz = (int)flz + s;

    const float wx[2] = {1.0f - ax, ax};
    const float wy[2] = {1.0f - ay, ay};
    const float wz[2] = {1.0f - az, az};

    float* grid = out + (size_t)b * (size_t)gpb;
    const int base = (ix * G + iy) * G + iz;

#pragma unroll
    for (int dx = 0; dx < 2; ++dx) {
#pragma unroll
        for (int dy = 0; dy < 2; ++dy) {
#pragma unroll
            for (int dz = 0; dz < 2; ++dz) {
                const int f = base + (dx * G + dy) * G + dz;
                atomicAdd(&grid[f], wx[dx] * wy[dy] * wz[dz]);
            }
        }
    }
}

extern "C" void kernel_launch(void* const* d_in, const int* in_sizes, int n_in,
                              void* d_out, int out_size, void* d_ws, size_t ws_size,
                              hipStream_t stream) {
    const float* pts = (const float*)d_in[0];
    const int* scale_p = (const int*)d_in[1];
    float* out = (float*)d_out;

    const int total_pts = in_sizes[0] / 3;   // B*N points

    // Harness poisons d_out with 0xAA before every timed launch -> zero it.
    hipMemsetAsync(d_out, 0, (size_t)out_size * sizeof(float), stream);

    const int threads = 256;
    const int blocks = (total_pts + threads - 1) / threads;
    Gridding_kernel<<<blocks, threads, 0, stream>>>(pts, scale_p, out, total_pts, out_size);
}